// Round 1
// baseline (180.192 us; speedup 1.0000x reference)
//
#include <hip/hip_runtime.h>

// Problem constants (match reference)
constexpr int B = 32, N = 256, C = 3, H = 512, W = 512, K = 32;

typedef float f32x4 __attribute__((ext_vector_type(4)));

// Block = 256 threads = one bn cell across ALL 3 channels:
// 32 rows x 8 float4-chunks per plane, 3 planes per thread.
// All patch parameters (bn, mu) are block-uniform -> scalar regs + s_load.
__global__ __launch_bounds__(256) void rgte_kernel(
    const float* __restrict__ img,
    const int*   __restrict__ mu,
    const float* __restrict__ gauss,
    float*       __restrict__ out)
{
    // XCD-chunked swizzle: grid = B*N = 8192 blocks, 8 XCDs, chunk = 1024.
    // blockIdx round-robins across XCDs (bid % 8), so XCD i receives the
    // contiguous bn range [i*1024, (i+1)*1024): its resident blocks share a
    // single b image slice (3 MB) -> fits the 4 MB per-XCD L2.
    const int bid = blockIdx.x;
    const int bn  = (bid & 7) * (B * N / 8) + (bid >> 3);
    const int b   = bn >> 8;                 // N = 256

    // Block-uniform: compiler keeps these in SGPRs, mu via s_load.
    const int mu0 = mu[2 * bn];
    const int mu1 = mu[2 * bn + 1];

    const int local = threadIdx.x;
    const int kx4   = local & 7;             // 8 float4 per K-row
    const int ky    = local >> 3;            // 32 rows

    constexpr int PLANE = H * W;
    const float* row = img + ((b * C * H + mu0 + ky) * W + mu1 + kx4 * 4);

    // Three independent (4B-aligned) 16B loads in flight — gfx9+ global HW
    // handles unaligned dwordx4. 3x the memory-level parallelism per wave.
    f32x4 v0 = *reinterpret_cast<const f32x4*>(row);
    f32x4 v1 = *reinterpret_cast<const f32x4*>(row + PLANE);
    f32x4 v2 = *reinterpret_cast<const f32x4*>(row + 2 * PLANE);

    // Gaussian chunk is 16B-aligned and L1-resident (4 KB total), read once
    // for all 3 channels.
    f32x4 g = *reinterpret_cast<const f32x4*>(gauss + ky * K + kx4 * 4);

    // Streaming output: nontemporal to avoid evicting the 12.6 MB image
    // from L2 with the 96 MiB write.
    // out element = bn*3072 + c*1024 + ky*32 + kx4*4  -> as f32x4:
    // bn*768 + c*256 + local
    f32x4* out4 = reinterpret_cast<f32x4*>(out) + (bn * (C * 256) + local);
    __builtin_nontemporal_store(v0 * g, out4);
    __builtin_nontemporal_store(v1 * g, out4 + 256);
    __builtin_nontemporal_store(v2 * g, out4 + 512);
}

extern "C" void kernel_launch(void* const* d_in, const int* in_sizes, int n_in,
                              void* d_out, int out_size, void* d_ws, size_t ws_size,
                              hipStream_t stream) {
    const float* img   = (const float*)d_in[0];
    const int*   mu    = (const int*)d_in[1];
    const float* gauss = (const float*)d_in[2];
    float*       out   = (float*)d_out;

    rgte_kernel<<<B * N, 256, 0, stream>>>(img, mu, gauss, out);
}

// Round 2
// 179.996 us; speedup vs baseline: 1.0011x; 1.0011x over previous
//
#include <hip/hip_runtime.h>

// Problem constants (match reference)
constexpr int B = 32, N = 256, C = 3, H = 512, W = 512, K = 32;

typedef float f32x4 __attribute__((ext_vector_type(4)));

// Block = 256 threads = one bn cell across ALL 3 channels:
// 32 rows x 8 float4-chunks per plane, 3 planes per thread.
// All patch parameters (bn, mu) are block-uniform -> scalar regs + s_load.
__global__ __launch_bounds__(256) void rgte_kernel(
    const float* __restrict__ img,
    const int*   __restrict__ mu,
    const float* __restrict__ gauss,
    float*       __restrict__ out)
{
    // XCD-chunked swizzle: grid = B*N = 8192 blocks, 8 XCDs, chunk = 1024.
    // XCD i receives the contiguous bn range [i*1024, (i+1)*1024): its
    // resident blocks share a single b image slice (3 MB) -> fits 4 MB L2.
    const int bid = blockIdx.x;
    const int bn  = (bid & 7) * (B * N / 8) + (bid >> 3);
    const int b   = bn >> 8;                 // N = 256

    // Block-uniform: compiler keeps these in SGPRs, mu via s_load.
    const int mu0 = mu[2 * bn];
    const int mu1 = mu[2 * bn + 1];

    const int local = threadIdx.x;
    const int kx4   = local & 7;             // 8 float4 per K-row
    const int ky    = local >> 3;            // 32 rows

    constexpr int PLANE = H * W;
    const float* row = img + ((b * C * H + mu0 + ky) * W + mu1 + kx4 * 4);

    // Three independent (4B-aligned) 16B loads in flight — gfx9+ global HW
    // handles unaligned dwordx4. 3x memory-level parallelism per wave.
    f32x4 v0 = *reinterpret_cast<const f32x4*>(row);
    f32x4 v1 = *reinterpret_cast<const f32x4*>(row + PLANE);
    f32x4 v2 = *reinterpret_cast<const f32x4*>(row + 2 * PLANE);

    // Gaussian chunk is 16B-aligned and L1-resident (4 KB total), read once
    // for all 3 channels.
    f32x4 g = *reinterpret_cast<const f32x4*>(gauss + ky * K + kx4 * 4);

    // REGULAR stores this round (single-variable A/B vs nontemporal).
    // Theory: NT bypasses L2 write-combining and may cap well below the
    // 6.4 TB/s the fill kernels reach with plain stores. Image eviction is
    // a non-issue: 12.6 MB image stays LLC-resident (256 MB) either way.
    // out element = bn*3072 + c*1024 + ky*32 + kx4*4  -> as f32x4:
    // bn*768 + c*256 + local
    f32x4* out4 = reinterpret_cast<f32x4*>(out) + (bn * (C * 256) + local);
    out4[0]   = v0 * g;
    out4[256] = v1 * g;
    out4[512] = v2 * g;
}

extern "C" void kernel_launch(void* const* d_in, const int* in_sizes, int n_in,
                              void* d_out, int out_size, void* d_ws, size_t ws_size,
                              hipStream_t stream) {
    const float* img   = (const float*)d_in[0];
    const int*   mu    = (const int*)d_in[1];
    const float* gauss = (const float*)d_in[2];
    float*       out   = (float*)d_out;

    rgte_kernel<<<B * N, 256, 0, stream>>>(img, mu, gauss, out);
}